// Round 5
// baseline (223.892 us; speedup 1.0000x reference)
//
#include <hip/hip_runtime.h>
#include <hip/hip_bf16.h>

// DiagonalEmbedder: out[b,i] = 0.5 * ( x2@inv.T - 2 x@(mean*inv).T + c_i )
//   c_i = sum(mean^2*inv) + sum(log d) + sum(inv) - DIM
// One bf16 MFMA GEMM, fp32 emulated via hi/lo split:
//   A' = [Ah | Ah | Al]  (4096 x 768),  B' = [Bh | Bl | Bh]  (8192 x 768)
//   dot(A',B') = Ah.Bh + Ah.Bl + Al.Bh  (fp32 AGPR accum)  [passed r2, absmax 1.0]

#define BATCH 4096
#define N_IN  8192
#define DIM   128
#define KP    768           // 3 * 2*DIM
#define PD_THR 1e-6f

#define BM 128
#define BN 128
#define BK 64

typedef __attribute__((ext_vector_type(4))) float f32x4;
typedef __attribute__((ext_vector_type(8))) short bf16x8;

static __device__ __forceinline__ unsigned short f2bf(float v) {
    union { __hip_bfloat16 h; unsigned short u; } cv;
    cv.h = __float2bfloat16(v);
    return cv.u;
}
static __device__ __forceinline__ float bf2f(unsigned short u) {
    union { unsigned short u; __hip_bfloat16 h; } cv;
    cv.u = u;
    return __bfloat162float(cv.h);
}

// ---------------- prep A: features [x^2, x] split hi/lo ----------------
__global__ void prep_a_kernel(const float* __restrict__ x,
                              unsigned short* __restrict__ Ap) {
    int t = blockIdx.x * 256 + threadIdx.x;          // 0 .. BATCH*DIM
    int row = t >> 7;
    int d   = t & 127;
    float v  = x[t];
    float x2 = v * v;
    unsigned short x2h = f2bf(x2);
    unsigned short x2l = f2bf(x2 - bf2f(x2h));
    unsigned short xh  = f2bf(v);
    unsigned short xl  = f2bf(v - bf2f(xh));
    unsigned short* a = Ap + (size_t)row * KP;
    a[d]       = x2h;  a[128 + d] = xh;    // Ah
    a[256 + d] = x2h;  a[384 + d] = xh;    // Ah (dup, pairs with Bl)
    a[512 + d] = x2l;  a[640 + d] = xl;    // Al (pairs with Bh)
}

// ------- prep B: features [inv, -2*mean*inv] split hi/lo + c_i ---------
__global__ void prep_b_kernel(const float* __restrict__ mean,
                              const float* __restrict__ diag,
                              unsigned short* __restrict__ Bp,
                              float* __restrict__ cvec) {
    int wave = threadIdx.x >> 6, lane = threadIdx.x & 63;
    int row = blockIdx.x * 4 + wave;                 // one wave per row
    const float* mrow = mean + (size_t)row * DIM;
    const float* drow = diag + (size_t)row * DIM;
    unsigned short* b = Bp + (size_t)row * KP;
    float csum = 0.0f;
#pragma unroll
    for (int j = 0; j < 2; ++j) {
        int d = lane + 64 * j;
        float m   = mrow[d];
        float dd  = fmaxf(drow[d], PD_THR);
        float inv = 1.0f / dd;
        float fm  = -2.0f * m * inv;
        csum += m * m * inv + logf(dd) + inv;
        unsigned short ih = f2bf(inv);
        unsigned short il = f2bf(inv - bf2f(ih));
        unsigned short fh = f2bf(fm);
        unsigned short fl = f2bf(fm - bf2f(fh));
        b[d]       = ih;  b[128 + d] = fh;   // Bh
        b[256 + d] = il;  b[384 + d] = fl;   // Bl
        b[512 + d] = ih;  b[640 + d] = fh;   // Bh (dup)
    }
#pragma unroll
    for (int off = 32; off > 0; off >>= 1) csum += __shfl_down(csum, off);
    if (lane == 0) cvec[row] = csum - (float)DIM;
}

// ---------------- GEMM: C = A'(MxK) * B'(NxK)^T, m97 structure ----------------
// 128x128 tile, 4 waves (2x2), each wave 64x64 via 4x4 frags of 16x16x32 bf16.
// Epilogue: per-wave LDS transpose -> float4 NON-TEMPORAL stores (keep L3 for
// the feature panels; r2 showed FETCH_SIZE=107MB from write-stream eviction).
__global__ void __launch_bounds__(256)
kl_gemm(const unsigned short* __restrict__ Ap,   // [BATCH][KP]
        const unsigned short* __restrict__ Bp,   // [N_IN][KP]
        const float* __restrict__ cvec,          // [N_IN]
        float* __restrict__ out) {               // [BATCH][N_IN]
    __shared__ __align__(16) unsigned short lds_a[BM * BK];  // 16 KB, linear [128][64]
    __shared__ __align__(16) unsigned short lds_b[BM * BK];  // 16 KB

    // Bijective XCD-aware swizzle (T1): nwg=2048, 8 XCDs, 2048%8==0.
    int bid0 = blockIdx.x;
    int bid  = (bid0 & 7) * ((BATCH / BM) * (N_IN / BN) / 8) + (bid0 >> 3);
    int bx = bid & 31;            // M tile (32); consecutive swz ids share B panel
    int by = bid >> 5;
    int m0 = bx * BM;
    int n0 = by * BN;

    int tid  = threadIdx.x;
    int wave = tid >> 6, lane = tid & 63;
    int wr = wave >> 1, wc = wave & 1;

    f32x4 acc[4][4];
#pragma unroll
    for (int m = 0; m < 4; ++m)
#pragma unroll
        for (int n = 0; n < 4; ++n) acc[m][n] = (f32x4){0.f, 0.f, 0.f, 0.f};

    // staging: each wave stages 4 contiguous 1KB chunks per tile.
    const int srow = wave * 32 + (lane >> 3);   // + j*8
    const int scol = (lane & 7) * 8;            // element col within BK

    for (int k0 = 0; k0 < KP; k0 += BK) {
#pragma unroll
        for (int j = 0; j < 4; ++j) {
            int r = srow + j * 8;
            const unsigned short* ga = Ap + (size_t)(m0 + r) * KP + k0 + scol;
            const unsigned short* gb = Bp + (size_t)(n0 + r) * KP + k0 + scol;
            unsigned short* la = lds_a + (wave * 4 + j) * 512;
            unsigned short* lb = lds_b + (wave * 4 + j) * 512;
            __builtin_amdgcn_global_load_lds(
                (const __attribute__((address_space(1))) void*)ga,
                (__attribute__((address_space(3))) void*)la, 16, 0, 0);
            __builtin_amdgcn_global_load_lds(
                (const __attribute__((address_space(1))) void*)gb,
                (__attribute__((address_space(3))) void*)lb, 16, 0, 0);
        }
        __syncthreads();   // drains vmcnt(0): staged data visible

#pragma unroll
        for (int kk = 0; kk < BK; kk += 32) {
            bf16x8 af[4], bfr[4];
#pragma unroll
            for (int m = 0; m < 4; ++m)
                af[m] = *(const bf16x8*)&lds_a[(wr * 64 + m * 16 + (lane & 15)) * BK
                                               + kk + (lane >> 4) * 8];
#pragma unroll
            for (int n = 0; n < 4; ++n)
                bfr[n] = *(const bf16x8*)&lds_b[(wc * 64 + n * 16 + (lane & 15)) * BK
                                                + kk + (lane >> 4) * 8];
#pragma unroll
            for (int m = 0; m < 4; ++m)
#pragma unroll
                for (int n = 0; n < 4; ++n)
                    acc[m][n] = __builtin_amdgcn_mfma_f32_16x16x32_bf16(
                        af[m], bfr[n], acc[m][n], 0, 0, 0);
        }
        __syncthreads();   // protect LDS before next stage
    }

    // ---- epilogue: LDS bounce to get float4-contiguous rows, nt stores ----
    // acc[m][n][r] belongs to row m0+wr*64+m*16+(lane>>4)*4+r,
    //                      col n0+wc*64+n*16+(lane&15)   (m89-verified layout)
    float* lbw = (float*)lds_a + wave * 1024;   // 4KB per wave (16 rows x 64 cols)
    const int crow0 = m0 + wr * 64;
    const int ccol0 = n0 + wc * 64;
    const int lr = (lane >> 4) << 2;            // 0,4,8,12
    const int lc = lane & 15;
#pragma unroll
    for (int m = 0; m < 4; ++m) {
        __syncthreads();   // previous m's reads complete before overwrite
#pragma unroll
        for (int n = 0; n < 4; ++n)
#pragma unroll
            for (int r = 0; r < 4; ++r)
                lbw[(lr + r) * 64 + n * 16 + lc] = acc[m][n][r];
        __syncthreads();   // writes visible
#pragma unroll
        for (int q = 0; q < 4; ++q) {
            int flat = q * 256 + lane * 4;      // covers 16x64 tile
            int row  = flat >> 6;
            int col  = flat & 63;
            f32x4 v  = *(const f32x4*)&lbw[flat];
            f32x4 c4 = *(const f32x4*)&cvec[ccol0 + col];
            f32x4 o  = (v + c4) * 0.5f;
            __builtin_nontemporal_store(
                o, (f32x4*)&out[(size_t)(crow0 + m * 16 + row) * N_IN + ccol0 + col]);
        }
    }
}

extern "C" void kernel_launch(void* const* d_in, const int* in_sizes, int n_in_args,
                              void* d_out, int out_size, void* d_ws, size_t ws_size,
                              hipStream_t stream) {
    (void)in_sizes; (void)n_in_args; (void)out_size; (void)ws_size;
    const float* x    = (const float*)d_in[0];
    const float* mean = (const float*)d_in[1];
    const float* diag = (const float*)d_in[2];
    float* out = (float*)d_out;

    char* ws = (char*)d_ws;
    unsigned short* Bp = (unsigned short*)ws;                              // 12.0 MB
    unsigned short* Ap = (unsigned short*)(ws + (size_t)N_IN * KP * 2);    //  6.0 MB
    float* cvec = (float*)(ws + (size_t)N_IN * KP * 2 + (size_t)BATCH * KP * 2); // 32 KB

    prep_a_kernel<<<BATCH * DIM / 256, 256, 0, stream>>>(x, Ap);
    prep_b_kernel<<<N_IN / 4, 256, 0, stream>>>(mean, diag, Bp, cvec);
    kl_gemm<<<(BATCH / BM) * (N_IN / BN), 256, 0, stream>>>(Ap, Bp, cvec, out);
}

// Round 6
// 209.459 us; speedup vs baseline: 1.0689x; 1.0689x over previous
//
#include <hip/hip_runtime.h>
#include <hip/hip_bf16.h>

// DiagonalEmbedder: out[b,i] = 0.5 * ( x2@inv.T - 2 x@(mean*inv).T + c_i )
//   c_i = sum(mean^2*inv) + sum(log d) + sum(inv) - DIM
// One bf16 MFMA GEMM, fp32 emulated via 3-term hi/lo split (passed r2/r5):
//   A' = [Ah | Ah | Al] (4096x768),  B' = [Bh | Bl | Bh] (8192x768)
// r5 counters: GEMM 103us, MfmaUtil 20%, bank-conflict 2e7, nothing saturated
// -> latency/barrier-bound. This round: 256^2 tile, 8 waves, dbuf LDS,
// counted-vmcnt pipeline (T3+T4), slot-XOR LDS swizzle (T2, both-sides via
// pre-swizzled global source), setprio (T5).

#define BATCH 4096
#define N_IN  8192
#define DIM   128
#define KP    768           // 3 * 2*DIM
#define PD_THR 1e-6f

#define BM 256
#define BN 256
#define BK 64
#define NT (KP / BK)        // 12 K-tiles

typedef __attribute__((ext_vector_type(4))) float f32x4;
typedef __attribute__((ext_vector_type(8))) short bf16x8;

static __device__ __forceinline__ unsigned short f2bf(float v) {
    union { __hip_bfloat16 h; unsigned short u; } cv;
    cv.h = __float2bfloat16(v);
    return cv.u;
}
static __device__ __forceinline__ float bf2f(unsigned short u) {
    union { unsigned short u; __hip_bfloat16 h; } cv;
    cv.u = u;
    return __bfloat162float(cv.h);
}

// ---------------- prep A: features [x^2, x] split hi/lo ----------------
__global__ void prep_a_kernel(const float* __restrict__ x,
                              unsigned short* __restrict__ Ap) {
    int t = blockIdx.x * 256 + threadIdx.x;
    int row = t >> 7;
    int d   = t & 127;
    float v  = x[t];
    float x2 = v * v;
    unsigned short x2h = f2bf(x2);
    unsigned short x2l = f2bf(x2 - bf2f(x2h));
    unsigned short xh  = f2bf(v);
    unsigned short xl  = f2bf(v - bf2f(xh));
    unsigned short* a = Ap + (size_t)row * KP;
    a[d]       = x2h;  a[128 + d] = xh;    // Ah
    a[256 + d] = x2h;  a[384 + d] = xh;    // Ah (dup, pairs with Bl)
    a[512 + d] = x2l;  a[640 + d] = xl;    // Al (pairs with Bh)
}

// ------- prep B: features [inv, -2*mean*inv] split hi/lo + c_i ---------
__global__ void prep_b_kernel(const float* __restrict__ mean,
                              const float* __restrict__ diag,
                              unsigned short* __restrict__ Bp,
                              float* __restrict__ cvec) {
    int wave = threadIdx.x >> 6, lane = threadIdx.x & 63;
    int row = blockIdx.x * 4 + wave;
    const float* mrow = mean + (size_t)row * DIM;
    const float* drow = diag + (size_t)row * DIM;
    unsigned short* b = Bp + (size_t)row * KP;
    float csum = 0.0f;
#pragma unroll
    for (int j = 0; j < 2; ++j) {
        int d = lane + 64 * j;
        float m   = mrow[d];
        float dd  = fmaxf(drow[d], PD_THR);
        float inv = 1.0f / dd;
        float fm  = -2.0f * m * inv;
        csum += m * m * inv + logf(dd) + inv;
        unsigned short ih = f2bf(inv);
        unsigned short il = f2bf(inv - bf2f(ih));
        unsigned short fh = f2bf(fm);
        unsigned short fl = f2bf(fm - bf2f(fh));
        b[d]       = ih;  b[128 + d] = fh;   // Bh
        b[256 + d] = il;  b[384 + d] = fl;   // Bl
        b[512 + d] = ih;  b[640 + d] = fh;   // Bh (dup)
    }
#pragma unroll
    for (int off = 32; off > 0; off >>= 1) csum += __shfl_down(csum, off);
    if (lane == 0) cvec[row] = csum - (float)DIM;
}

// -------------- GEMM: C = A'(MxK) * B'(NxK)^T, 256^2 counted-vmcnt --------------
// 8 waves (2M x 4N), each wave computes 128x64 via acc[8][4] of 16x16x32 frags.
// LDS: 2 buffers x (A 256x64 + B 256x64) bf16 = 128 KiB. 1 block/CU.
// Pipeline: STAGE(t),STAGE(t+1) prologue; per iter: vmcnt(8) [t's 8 loads done,
// t+1's 8 in flight] -> barrier -> compute(t) -> barrier -> STAGE(t+2).
// Never drains vmcnt to 0 in the main loop (T4); last iter peeled with vmcnt(0).
// LDS swizzle: physical 16B-slot s of row r holds logical slot s^(r&7);
// realized by pre-swizzling the per-lane GLOBAL source (LDS dest stays linear,
// rule #21), read back with the same XOR. 16-way conflict -> 2-way (free).
__global__ void __launch_bounds__(512, 2)
kl_gemm(const unsigned short* __restrict__ Ap,   // [BATCH][KP]
        const unsigned short* __restrict__ Bp,   // [N_IN][KP]
        const float* __restrict__ cvec,          // [N_IN]
        float* __restrict__ out) {               // [BATCH][N_IN]
    __shared__ __align__(16) unsigned short lds[2][2 * BM * BK];  // 128 KiB

    // Bijective XCD swizzle: 512 blocks, 512 % 8 == 0.
    int bid0 = blockIdx.x;
    int bid  = (bid0 & 7) * 64 + (bid0 >> 3);
    int bx = bid & 15;            // 16 M-tiles (fast: consecutive ids share B panel)
    int by = bid >> 4;            // 32 N-tiles
    int m0 = bx * BM, n0 = by * BN;

    int tid  = threadIdx.x;
    int wave = tid >> 6, lane = tid & 63;
    int wr = wave >> 2, wc = wave & 3;      // 2 x 4 wave grid

    const int lrow  = lane >> 3;            // 0..7: row within 8-row stage chunk
    const int lslot = (lane & 7) ^ lrow;    // pre-swizzled 16B source slot

    // Staging bases. Wave w, instr j stages rows [j*64 + w*8, +8) of the tile:
    // 64 lanes x 16B = 1KB, LDS dest linear (wave-uniform base + lane*16).
    const unsigned short* gA = Ap + (size_t)(m0 + wave * 8 + lrow) * KP + lslot * 8;
    const unsigned short* gB = Bp + (size_t)(n0 + wave * 8 + lrow) * KP + lslot * 8;

    f32x4 acc[8][4];
#pragma unroll
    for (int m = 0; m < 8; ++m)
#pragma unroll
        for (int n = 0; n < 4; ++n) acc[m][n] = (f32x4){0.f, 0.f, 0.f, 0.f};

    // 8 global_load_lds per wave per K-tile (4 A + 4 B).
    auto STAGE = [&](int b, int t) {
        int k0 = t * BK;
#pragma unroll
        for (int j = 0; j < 4; ++j)
            __builtin_amdgcn_global_load_lds(
                (const __attribute__((address_space(1))) void*)(gA + (size_t)j * 64 * KP + k0),
                (__attribute__((address_space(3))) void*)&lds[b][(wave * 8 + j * 64) * 64],
                16, 0, 0);
#pragma unroll
        for (int j = 0; j < 4; ++j)
            __builtin_amdgcn_global_load_lds(
                (const __attribute__((address_space(1))) void*)(gB + (size_t)j * 64 * KP + k0),
                (__attribute__((address_space(3))) void*)&lds[b][16384 + (wave * 8 + j * 64) * 64],
                16, 0, 0);
    };

    auto COMPUTE = [&](int b) {
        const unsigned short* La = &lds[b][0];
        const unsigned short* Lb = &lds[b][16384];
#pragma unroll
        for (int kk = 0; kk < BK; kk += 32) {
            // logical slot = kk/8 + (lane>>4); physical = logical ^ (row&7),
            // row&7 == lane&7 for all fragment rows (row = 16*m' + (lane&15)).
            const int phys = (((kk >> 3) + (lane >> 4)) ^ (lane & 7)) * 8;
            bf16x8 af[8], bf[4];
#pragma unroll
            for (int m = 0; m < 8; ++m)
                af[m] = *(const bf16x8*)&La[(wr * 128 + m * 16 + (lane & 15)) * 64 + phys];
#pragma unroll
            for (int n = 0; n < 4; ++n)
                bf[n] = *(const bf16x8*)&Lb[(wc * 64 + n * 16 + (lane & 15)) * 64 + phys];
            __builtin_amdgcn_s_setprio(1);
#pragma unroll
            for (int m = 0; m < 8; ++m)
#pragma unroll
                for (int n = 0; n < 4; ++n)
                    acc[m][n] = __builtin_amdgcn_mfma_f32_16x16x32_bf16(
                        af[m], bf[n], acc[m][n], 0, 0, 0);
            __builtin_amdgcn_s_setprio(0);
        }
    };

    STAGE(0, 0);
    STAGE(1, 1);
#pragma unroll 1
    for (int t = 0; t < NT - 1; ++t) {
        // Outstanding: t's 8 + (t+1)'s 8 = 16. Wait to 8 => t's complete,
        // (t+1)'s stay in flight across the barrier (T4: never drain).
        asm volatile("s_waitcnt vmcnt(8)" ::: "memory");
        __builtin_amdgcn_s_barrier();            // all waves' t-loads landed
        __builtin_amdgcn_sched_barrier(0);       // no ds_read hoists above (rule #18)
        COMPUTE(t & 1);
        __builtin_amdgcn_s_barrier();            // all waves done reading buf(t)
        __builtin_amdgcn_sched_barrier(0);       // no STAGE sinks above barrier
        if (t + 2 < NT) STAGE(t & 1, t + 2);     // overwrite freed buffer
    }
    // Peeled last tile: only its own 8 loads outstanding -> must drain fully.
    asm volatile("s_waitcnt vmcnt(0)" ::: "memory");
    __builtin_amdgcn_s_barrier();
    __builtin_amdgcn_sched_barrier(0);
    COMPUTE((NT - 1) & 1);
    __builtin_amdgcn_s_barrier();                // all frag reads done before bounce
    __builtin_amdgcn_sched_barrier(0);

    // ---- epilogue: per-wave LDS bounce -> float4 nt stores ----
    // acc[m][n][r] -> row crow0 + m*16 + (lane>>4)*4 + r, col ccol0 + n*16 + (lane&15)
    float* lbw = (float*)&lds[0][0] + wave * 1024;   // 4KB/wave, disjoint regions
    const int crow0 = m0 + wr * 128;
    const int ccol0 = n0 + wc * 64;
    const int lr = (lane >> 4) << 2;
    const int lc = lane & 15;
#pragma unroll
    for (int m = 0; m < 8; ++m) {
#pragma unroll
        for (int n = 0; n < 4; ++n)
#pragma unroll
            for (int r = 0; r < 4; ++r)
                lbw[(lr + r) * 64 + n * 16 + lc] = acc[m][n][r];
        // wave-private region: compiler-inserted lgkmcnt orders write->read
#pragma unroll
        for (int q = 0; q < 4; ++q) {
            int flat = q * 256 + lane * 4;      // 16x64 f32 tile, stride-1 reads
            int row  = flat >> 6;
            int col  = flat & 63;
            f32x4 v  = *(const f32x4*)&lbw[flat];
            f32x4 c4 = *(const f32x4*)&cvec[ccol0 + col];
            f32x4 o  = (v + c4) * 0.5f;
            __builtin_nontemporal_store(
                o, (f32x4*)&out[(size_t)(crow0 + m * 16 + row) * N_IN + ccol0 + col]);
        }
    }
}

extern "C" void kernel_launch(void* const* d_in, const int* in_sizes, int n_in_args,
                              void* d_out, int out_size, void* d_ws, size_t ws_size,
                              hipStream_t stream) {
    (void)in_sizes; (void)n_in_args; (void)out_size; (void)ws_size;
    const float* x    = (const float*)d_in[0];
    const float* mean = (const float*)d_in[1];
    const float* diag = (const float*)d_in[2];
    float* out = (float*)d_out;

    char* ws = (char*)d_ws;
    unsigned short* Bp = (unsigned short*)ws;                              // 12.0 MB
    unsigned short* Ap = (unsigned short*)(ws + (size_t)N_IN * KP * 2);    //  6.0 MB
    float* cvec = (float*)(ws + (size_t)N_IN * KP * 2 + (size_t)BATCH * KP * 2); // 32 KB

    prep_a_kernel<<<BATCH * DIM / 256, 256, 0, stream>>>(x, Ap);
    prep_b_kernel<<<N_IN / 4, 256, 0, stream>>>(mean, diag, Bp, cvec);
    kl_gemm<<<(BATCH / BM) * (N_IN / BN), 512, 0, stream>>>(Ap, Bp, cvec, out);
}

// Round 7
// 188.907 us; speedup vs baseline: 1.1852x; 1.1088x over previous
//
#include <hip/hip_runtime.h>
#include <hip/hip_bf16.h>

// DiagonalEmbedder: out[b,i] = 0.5 * ( x2@inv.T - 2 x@(mean*inv).T + c_i )
//   c_i = sum(mean^2*inv) + sum(log d) + sum(inv) - DIM
// r6 post-mortem: staging-supply-bound (vmcnt wait ~70% of iter; blended
// L2/L3/HBM ~4.6 TB/s vs 17 TB/s demand). This round:
//  (1) 2-term split, K=512: A' = [FAh | FAl] (4096x512), B = single-bf16
//      [inv, -2*mean*inv] (8192x256) consumed twice (t&3 wrap). Error =
//      FA.dB ~ 0.08 abs (inv==1 exact in bf16 for this data).
//  (2) per-XCD 8x8 rectangular tile groups: co-resident working set ~3MB
//      fits per-XCD L2 -> staging becomes L2-hit.
// Pipeline unchanged from r6 (counted vmcnt(8), dbuf, slot-XOR swizzle).

#define BATCH 4096
#define N_IN  8192
#define DIM   128
#define KPA   512           // A': [FAh(256) | FAl(256)]
#define KPB   256           // B: stored once, logical K duplicates it
#define PD_THR 1e-6f

#define BM 256
#define BN 256
#define BK 64
#define NT (KPA / BK)       // 8 K-tiles

typedef __attribute__((ext_vector_type(4))) float f32x4;
typedef __attribute__((ext_vector_type(8))) short bf16x8;

static __device__ __forceinline__ unsigned short f2bf(float v) {
    union { __hip_bfloat16 h; unsigned short u; } cv;
    cv.h = __float2bfloat16(v);
    return cv.u;
}
static __device__ __forceinline__ float bf2f(unsigned short u) {
    union { unsigned short u; __hip_bfloat16 h; } cv;
    cv.u = u;
    return __bfloat162float(cv.h);
}

// ------------- prep A: [x^2, x] hi/lo -> [FAh(256) | FAl(256)] -------------
__global__ void prep_a_kernel(const float* __restrict__ x,
                              unsigned short* __restrict__ Ap) {
    int t = blockIdx.x * 256 + threadIdx.x;   // 0 .. BATCH*DIM
    int row = t >> 7;
    int d   = t & 127;
    float v  = x[t];
    float x2 = v * v;
    unsigned short x2h = f2bf(x2);
    unsigned short x2l = f2bf(x2 - bf2f(x2h));
    unsigned short xh  = f2bf(v);
    unsigned short xl  = f2bf(v - bf2f(xh));
    unsigned short* a = Ap + (size_t)row * KPA;
    a[d]       = x2h;  a[128 + d] = xh;    // FAh
    a[256 + d] = x2l;  a[384 + d] = xl;    // FAl
}

// ------- prep B: single-bf16 [inv, -2*mean*inv] (256 wide) + c_i ---------
__global__ void prep_b_kernel(const float* __restrict__ mean,
                              const float* __restrict__ diag,
                              unsigned short* __restrict__ Bp,
                              float* __restrict__ cvec) {
    int wave = threadIdx.x >> 6, lane = threadIdx.x & 63;
    int row = blockIdx.x * 4 + wave;
    const float* mrow = mean + (size_t)row * DIM;
    const float* drow = diag + (size_t)row * DIM;
    unsigned short* b = Bp + (size_t)row * KPB;
    float csum = 0.0f;
#pragma unroll
    for (int j = 0; j < 2; ++j) {
        int d = lane + 64 * j;
        float m   = mrow[d];
        float dd  = fmaxf(drow[d], PD_THR);
        float inv = 1.0f / dd;
        float fm  = -2.0f * m * inv;
        csum += m * m * inv + logf(dd) + inv;
        b[d]       = f2bf(inv);
        b[128 + d] = f2bf(fm);
    }
#pragma unroll
    for (int off = 32; off > 0; off >>= 1) csum += __shfl_down(csum, off);
    if (lane == 0) cvec[row] = csum - (float)DIM;
}

// ------------- GEMM: 256^2 tile, 8 waves, counted-vmcnt pipeline -------------
// Logical K = 512: tiles 0..7 of A' vs B-tiles (t&3) (B bytes consumed twice;
// second pass is L2-hot). LDS 2 x (A 32KB + B 32KB) = 128 KiB, 1 block/CU.
// Slot-XOR swizzle via pre-swizzled GLOBAL source (LDS dest linear, rule #21).
__global__ void __launch_bounds__(512, 2)
kl_gemm(const unsigned short* __restrict__ Ap,   // [BATCH][KPA]
        const unsigned short* __restrict__ Bp,   // [N_IN][KPB]
        const float* __restrict__ cvec,          // [N_IN]
        float* __restrict__ out) {               // [BATCH][N_IN]
    __shared__ __align__(16) unsigned short lds[2][2 * BM * BK];  // 128 KiB

    // Per-XCD rectangular grouping: xcd = bid%8 owns an 8x8 tile block
    // (grid 16x32 tiles = 2x4 groups of 8x8). Within a group, ids fill
    // bx-fastest so the ~32 co-resident blocks cover 8 bx x 4 by:
    // working set 8 A-panels(2MB) + 4 B-panels(0.5MB) < 4MiB L2.
    int bid0 = blockIdx.x;
    int xcd = bid0 & 7, g = bid0 >> 3;            // g in [0,64)
    int bx = (xcd & 1) * 8 + (g & 7);             // [0,16)
    int by = (xcd >> 1) * 8 + (g >> 3);           // [0,32)
    int m0 = bx * BM, n0 = by * BN;

    int tid  = threadIdx.x;
    int wave = tid >> 6, lane = tid & 63;
    int wr = wave >> 2, wc = wave & 3;            // 2 x 4 wave grid

    const int lrow  = lane >> 3;                  // row within 8-row chunk
    const int lslot = (lane & 7) ^ lrow;          // pre-swizzled 16B slot

    const unsigned short* gA = Ap + (size_t)(m0 + wave * 8 + lrow) * KPA + lslot * 8;
    const unsigned short* gB = Bp + (size_t)(n0 + wave * 8 + lrow) * KPB + lslot * 8;

    f32x4 acc[8][4];
#pragma unroll
    for (int m = 0; m < 8; ++m)
#pragma unroll
        for (int n = 0; n < 4; ++n) acc[m][n] = (f32x4){0.f, 0.f, 0.f, 0.f};

    // 8 global_load_lds per wave per K-tile (4 A + 4 B).
    auto STAGE = [&](int b, int t) {
        int k0a = t * BK;
        int k0b = (t & 3) * BK;                   // B wraps: stored once
#pragma unroll
        for (int j = 0; j < 4; ++j)
            __builtin_amdgcn_global_load_lds(
                (const __attribute__((address_space(1))) void*)(gA + (size_t)j * 64 * KPA + k0a),
                (__attribute__((address_space(3))) void*)&lds[b][(wave * 8 + j * 64) * 64],
                16, 0, 0);
#pragma unroll
        for (int j = 0; j < 4; ++j)
            __builtin_amdgcn_global_load_lds(
                (const __attribute__((address_space(1))) void*)(gB + (size_t)j * 64 * KPB + k0b),
                (__attribute__((address_space(3))) void*)&lds[b][16384 + (wave * 8 + j * 64) * 64],
                16, 0, 0);
    };

    auto COMPUTE = [&](int b) {
        const unsigned short* La = &lds[b][0];
        const unsigned short* Lb = &lds[b][16384];
#pragma unroll
        for (int kk = 0; kk < BK; kk += 32) {
            const int phys = ((((kk >> 3) + (lane >> 4))) ^ (lane & 7)) * 8;
            bf16x8 af[8], bf[4];
#pragma unroll
            for (int m = 0; m < 8; ++m)
                af[m] = *(const bf16x8*)&La[(wr * 128 + m * 16 + (lane & 15)) * 64 + phys];
#pragma unroll
            for (int n = 0; n < 4; ++n)
                bf[n] = *(const bf16x8*)&Lb[(wc * 64 + n * 16 + (lane & 15)) * 64 + phys];
            __builtin_amdgcn_s_setprio(1);
#pragma unroll
            for (int m = 0; m < 8; ++m)
#pragma unroll
                for (int n = 0; n < 4; ++n)
                    acc[m][n] = __builtin_amdgcn_mfma_f32_16x16x32_bf16(
                        af[m], bf[n], acc[m][n], 0, 0, 0);
            __builtin_amdgcn_s_setprio(0);
        }
    };

    STAGE(0, 0);
    STAGE(1, 1);
#pragma unroll 1
    for (int t = 0; t < NT - 1; ++t) {
        // 16 outstanding (t's 8 + t+1's 8); wait to 8 => t complete,
        // t+1 stays in flight across the barrier (T4: never drain in-loop).
        asm volatile("s_waitcnt vmcnt(8)" ::: "memory");
        __builtin_amdgcn_s_barrier();
        __builtin_amdgcn_sched_barrier(0);       // rule #18: pin ds_reads below
        COMPUTE(t & 1);
        __builtin_amdgcn_s_barrier();            // all waves done with buf(t)
        __builtin_amdgcn_sched_barrier(0);
        if (t + 2 < NT) STAGE(t & 1, t + 2);
    }
    asm volatile("s_waitcnt vmcnt(0)" ::: "memory");
    __builtin_amdgcn_s_barrier();
    __builtin_amdgcn_sched_barrier(0);
    COMPUTE((NT - 1) & 1);
    __builtin_amdgcn_s_barrier();                // frag reads done before bounce
    __builtin_amdgcn_sched_barrier(0);

    // ---- epilogue: per-wave LDS bounce -> float4 nt stores ----
    float* lbw = (float*)&lds[0][0] + wave * 1024;   // 4KB/wave, disjoint
    const int crow0 = m0 + wr * 128;
    const int ccol0 = n0 + wc * 64;
    const int lr = (lane >> 4) << 2;
    const int lc = lane & 15;
#pragma unroll
    for (int m = 0; m < 8; ++m) {
#pragma unroll
        for (int n = 0; n < 4; ++n)
#pragma unroll
            for (int r = 0; r < 4; ++r)
                lbw[(lr + r) * 64 + n * 16 + lc] = acc[m][n][r];
        // wave-private region: compiler lgkmcnt orders write->read
#pragma unroll
        for (int q = 0; q < 4; ++q) {
            int flat = q * 256 + lane * 4;
            int row  = flat >> 6;
            int col  = flat & 63;
            f32x4 v  = *(const f32x4*)&lbw[flat];
            f32x4 c4 = *(const f32x4*)&cvec[ccol0 + col];
            f32x4 o  = (v + c4) * 0.5f;
            __builtin_nontemporal_store(
                o, (f32x4*)&out[(size_t)(crow0 + m * 16 + row) * N_IN + ccol0 + col]);
        }
    }
}

extern "C" void kernel_launch(void* const* d_in, const int* in_sizes, int n_in_args,
                              void* d_out, int out_size, void* d_ws, size_t ws_size,
                              hipStream_t stream) {
    (void)in_sizes; (void)n_in_args; (void)out_size; (void)ws_size;
    const float* x    = (const float*)d_in[0];
    const float* mean = (const float*)d_in[1];
    const float* diag = (const float*)d_in[2];
    float* out = (float*)d_out;

    char* ws = (char*)d_ws;
    unsigned short* Bp = (unsigned short*)ws;                               // 4 MB
    unsigned short* Ap = (unsigned short*)(ws + (size_t)N_IN * KPB * 2);    // 4 MB
    float* cvec = (float*)(ws + (size_t)N_IN * KPB * 2 + (size_t)BATCH * KPA * 2);

    prep_a_kernel<<<BATCH * DIM / 256, 256, 0, stream>>>(x, Ap);
    prep_b_kernel<<<N_IN / 4, 256, 0, stream>>>(mean, diag, Bp, cvec);
    kl_gemm<<<(BATCH / BM) * (N_IN / BN), 512, 0, stream>>>(Ap, Bp, cvec, out);
}